// Round 4
// baseline (375.837 us; speedup 1.0000x reference)
//
#include <hip/hip_runtime.h>

typedef long long ll;

#define PPI   65536      // pixels per image (256*256)
#define NPIX  524288     // total pixels (8 images)
#define NCH   64         // feat channels
#define NB    16         // bottleneck channels
#define NC    64         // num_colors
#define BN_EPS 1e-5

// 1 pixel/thread, 256 threads/block -> 2048 blocks = 8 blocks/CU = 32 waves/CU.
// R3 counters showed Occupancy=19% (512-block grid) with HBM 19% / VALU 40%:
// latency-bound. Scalar 4B accesses stay fully coalesced (256B per wave-instr).

// ---------------------------------------------------------------------------
// k1: 1x1 conv (bias dropped — cancels under BN mean-subtraction), stash x
//     into the m-output region (channels 48..63), accumulate BN sum/sumsq.
// ---------------------------------------------------------------------------
__global__ __launch_bounds__(256, 8) void k_conv(const float* __restrict__ feat,
                                                 const float* __restrict__ wb,
                                                 double* __restrict__ gsum,
                                                 double* __restrict__ gsq,
                                                 float* __restrict__ xout)
{
    const int tid  = threadIdx.x;
    const int wave = tid >> 6, lane = tid & 63;
    const int b    = blockIdx.x >> 8;                 // 256 blocks per image
    const int p    = ((blockIdx.x & 255) << 8) + tid; // 1 pixel per thread
    const float* fb = feat + (ll)b * NCH * PPI + p;

    float acc[NB];
#pragma unroll
    for (int o = 0; o < NB; ++o) acc[o] = 0.f;

#pragma unroll 4
    for (int c = 0; c < NCH; ++c) {
        float f = fb[(ll)c * PPI];
#pragma unroll
        for (int o = 0; o < NB; ++o)
            acc[o] = fmaf(f, wb[o * NCH + c], acc[o]);  // wb wave-uniform -> s_load
    }

    // stash x in m[b][48+o][p] (k2 consumes then overwrites)
#pragma unroll
    for (int o = 0; o < NB; ++o)
        xout[((ll)(b * NC + 48 + o)) * PPI + p] = acc[o];

    // BN stats: wave shuffle-reduce, then block LDS reduce, then global atomic
    __shared__ float red_s[4][NB], red_q[4][NB];
#pragma unroll
    for (int o = 0; o < NB; ++o) {
        float s = acc[o];
        float q = acc[o] * acc[o];
#pragma unroll
        for (int off = 32; off > 0; off >>= 1) {
            s += __shfl_down(s, off);
            q += __shfl_down(q, off);
        }
        if (lane == 0) { red_s[wave][o] = s; red_q[wave][o] = q; }
    }
    __syncthreads();
    if (tid < NB) {
        atomicAdd(&gsum[tid], (double)red_s[0][tid] + red_s[1][tid] + red_s[2][tid] + red_s[3][tid]);
        atomicAdd(&gsq[tid],  (double)red_q[0][tid] + red_q[1][tid] + red_q[2][tid] + red_q[3][tid]);
    }
}

// ---------------------------------------------------------------------------
// k2: BN+ReLU on x (read from m region), logits, top-4, softmax, dense m,
//     per-pixel records, palette num/den accumulation.
//     NOTE: m_out deliberately NOT __restrict__ — x lives inside it.
// ---------------------------------------------------------------------------
__global__ __launch_bounds__(256, 8) void k_mask(const float* __restrict__ img,
                                                 const float* __restrict__ gamma,
                                                 const float* __restrict__ beta,
                                                 const float* __restrict__ wm,
                                                 const double* __restrict__ gsum,
                                                 const double* __restrict__ gsq,
                                                 float* __restrict__ den_g,
                                                 float* __restrict__ num_g,
                                                 float* m_out,
                                                 unsigned* __restrict__ idx_out,
                                                 float* __restrict__ sm_out)
{
    __shared__ float weff_l[NC][NB];
    __shared__ float den_loc[4][NC];
    __shared__ float num_loc[4][3 * NC];
    __shared__ float scl_l[NB], shf_l[NB];

    const int tid  = threadIdx.x;
    const int wave = tid >> 6;
    const int b    = blockIdx.x >> 8;
    const int p    = ((blockIdx.x & 255) << 8) + tid;

    for (int i = tid; i < NC * NB; i += 256) {
        int n = i >> 4, o = i & 15;
        weff_l[n][o] = 0.25f * (wm[n * NB + o] + wm[(64 + n) * NB + o] +
                                wm[(128 + n) * NB + o] + wm[(192 + n) * NB + o]);
    }
    for (int i = tid; i < 4 * NC; i += 256) den_loc[i >> 6][i & 63] = 0.f;
    for (int i = tid; i < 4 * 3 * NC; i += 256) num_loc[i / (3 * NC)][i % (3 * NC)] = 0.f;
    if (tid < NB) {
        double mu  = gsum[tid] * (1.0 / NPIX);
        double var = gsq[tid] * (1.0 / NPIX) - mu * mu;
        double sc  = (double)gamma[tid] / sqrt(var + BN_EPS);
        scl_l[tid] = (float)sc;
        shf_l[tid] = (float)((double)beta[tid] - mu * sc);
    }
    __syncthreads();

    // load x, BN + ReLU
    float xx[NB];
#pragma unroll
    for (int o = 0; o < NB; ++o)
        xx[o] = m_out[((ll)(b * NC + 48 + o)) * PPI + p];
#pragma unroll
    for (int o = 0; o < NB; ++o)
        xx[o] = fmaxf(0.f, fmaf(xx[o], scl_l[o], shf_l[o]));

    // streaming branchless top-4 (strict > keeps jax lowest-index tie-break)
    float tv[4];
    int   ti[4];
#pragma unroll
    for (int k = 0; k < 4; ++k) { tv[k] = -3.4e38f; ti[k] = 0; }

#pragma unroll 2
    for (int n = 0; n < NC; ++n) {
        const float* wr = weff_l[n];
        float v = 0.f;
#pragma unroll
        for (int o = 0; o < NB; ++o) v = fmaf(xx[o], wr[o], v);
        bool c0 = v > tv[0];
        bool c1 = v > tv[1];
        bool c2 = v > tv[2];
        bool c3 = v > tv[3];
        tv[3] = c2 ? tv[2] : fmaxf(v, tv[3]);
        ti[3] = c2 ? ti[2] : (c3 ? n : ti[3]);
        tv[2] = c1 ? tv[1] : fmaxf(v, tv[2]);
        ti[2] = c1 ? ti[1] : (c2 ? n : ti[2]);
        tv[1] = c0 ? tv[0] : fmaxf(v, tv[1]);
        ti[1] = c0 ? ti[0] : (c1 ? n : ti[1]);
        tv[0] = fmaxf(v, tv[0]);
        ti[0] = c0 ? n : ti[0];
    }

    // softmax over kept 4 (tv sorted desc)
    float e1 = expf(tv[1] - tv[0]);
    float e2 = expf(tv[2] - tv[0]);
    float e3 = expf(tv[3] - tv[0]);
    float rz = 1.f / (1.f + e1 + e2 + e3);
    float smx[4] = {rz, e1 * rz, e2 * rz, e3 * rz};

    // dense m write (overwrites the x stash at n=48..63 for this thread's pixel)
#pragma unroll 1
    for (int n = 0; n < NC; ++n) {
        float val = ((ti[0] == n) ? smx[0] : 0.f) + ((ti[1] == n) ? smx[1] : 0.f) +
                    ((ti[2] == n) ? smx[2] : 0.f) + ((ti[3] == n) ? smx[3] : 0.f);
        m_out[((ll)(b * NC + n)) * PPI + p] = val;
    }

    // per-pixel records (consumed by k3)
    ll gp = (ll)b * PPI + p;
    idx_out[gp] = (unsigned)ti[0] | ((unsigned)ti[1] << 8) |
                  ((unsigned)ti[2] << 16) | ((unsigned)ti[3] << 24);
#pragma unroll
    for (int k = 0; k < 4; ++k) sm_out[(ll)k * NPIX + gp] = smx[k];

    // palette accumulation (per-wave LDS copies to cut contention)
    float i0 = img[((ll)b * 3 + 0) * PPI + p];
    float i1 = img[((ll)b * 3 + 1) * PPI + p];
    float i2 = img[((ll)b * 3 + 2) * PPI + p];
#pragma unroll
    for (int k = 0; k < 4; ++k) {
        float s = smx[k];
        int   n = ti[k];
        atomicAdd(&den_loc[wave][n], s);
        atomicAdd(&num_loc[wave][0 * NC + n], s * i0);
        atomicAdd(&num_loc[wave][1 * NC + n], s * i1);
        atomicAdd(&num_loc[wave][2 * NC + n], s * i2);
    }
    __syncthreads();
    if (tid < NC)
        atomicAdd(&den_g[b * NC + tid],
                  den_loc[0][tid] + den_loc[1][tid] + den_loc[2][tid] + den_loc[3][tid]);
    if (tid < 3 * NC)
        atomicAdd(&num_g[(ll)b * 3 * NC + tid],
                  num_loc[0][tid] + num_loc[1][tid] + num_loc[2][tid] + num_loc[3][tid]);
}

// ---------------------------------------------------------------------------
// k3: palette finalize (per-block in LDS) + write palette + reconstruction
// ---------------------------------------------------------------------------
__global__ __launch_bounds__(256, 8) void k_recon(const unsigned* __restrict__ idx_in,
                                                  const float* __restrict__ sm_in,
                                                  const float* __restrict__ den_g,
                                                  const float* __restrict__ num_g,
                                                  float* __restrict__ pal_out,
                                                  float* __restrict__ t_out)
{
    __shared__ float pal_l[3][NC];
    __shared__ float rden[NC];
    const int tid = threadIdx.x;
    const int b   = blockIdx.x >> 8;
    const int p   = ((blockIdx.x & 255) << 8) + tid;

    if (tid < NC) rden[tid] = 1.f / (den_g[b * NC + tid] + 1e-8f);
    __syncthreads();
    if (tid < 3 * NC) {
        int c = tid >> 6, n = tid & 63;
        pal_l[c][n] = num_g[(ll)b * 3 * NC + tid] * rden[n];
    }
    __syncthreads();
    if ((blockIdx.x & 255) == 0 && tid < 3 * NC)
        pal_out[b * 3 * NC + tid] = pal_l[tid >> 6][tid & 63];

    ll gp = (ll)b * PPI + p;
    unsigned pk = idx_in[gp];
    int t0 = pk & 255, t1 = (pk >> 8) & 255, t2 = (pk >> 16) & 255, t3 = pk >> 24;
    float s0 = sm_in[gp];
    float s1 = sm_in[(ll)NPIX + gp];
    float s2 = sm_in[2ll * NPIX + gp];
    float s3 = sm_in[3ll * NPIX + gp];

#pragma unroll
    for (int c = 0; c < 3; ++c) {
        float v = s0 * pal_l[c][t0] + s1 * pal_l[c][t1] +
                  s2 * pal_l[c][t2] + s3 * pal_l[c][t3];
        t_out[((ll)b * 3 + c) * PPI + p] = v;
    }
}

// ---------------------------------------------------------------------------
extern "C" void kernel_launch(void* const* d_in, const int* in_sizes, int n_in,
                              void* d_out, int out_size, void* d_ws, size_t ws_size,
                              hipStream_t stream)
{
    const float* img   = (const float*)d_in[0];
    const float* feat  = (const float*)d_in[1];
    const float* wb    = (const float*)d_in[2];
    // d_in[3] = b_bneck: unused — bias cancels under BatchNorm mean-subtraction
    const float* gamma = (const float*)d_in[4];
    const float* beta  = (const float*)d_in[5];
    const float* wm    = (const float*)d_in[6];

    char* ws = (char*)d_ws;
    double*   gsum  = (double*)(ws + 0);      // 16 doubles
    double*   gsq   = (double*)(ws + 128);    // 16 doubles
    float*    den_g = (float*)(ws + 256);     // 8*64 floats
    float*    num_g = (float*)(ws + 2304);    // 8*3*64 floats  (end: 8448)
    unsigned* idx4  = (unsigned*)(ws + 8448);             // NPIX u32
    float*    smarr = (float*)(ws + 8448 + 4ll * NPIX);   // 4*NPIX f32

    float* t_out   = (float*)d_out;               // [8,3,256,256]
    float* m_out   = t_out + 3ll * NPIX;          // [8,64,256,256]
    float* pal_out = m_out + 64ll * NPIX;         // [8,3,64,1,1]

    hipMemsetAsync(ws, 0, 8448, stream);          // zero atomic accumulators

    k_conv <<<NPIX / 256, 256, 0, stream>>>(feat, wb, gsum, gsq, m_out);
    k_mask <<<NPIX / 256, 256, 0, stream>>>(img, gamma, beta, wm, gsum, gsq,
                                            den_g, num_g, m_out, idx4, smarr);
    k_recon<<<NPIX / 256, 256, 0, stream>>>(idx4, smarr, den_g, num_g, pal_out, t_out);
}

// Round 5
// 353.908 us; speedup vs baseline: 1.0620x; 1.0620x over previous
//
#include <hip/hip_runtime.h>

typedef long long ll;

#define PPI   65536      // pixels per image (256*256)
#define NPIX  524288     // total pixels (8 images)
#define NCH   64         // feat channels
#define NB    16         // bottleneck channels
#define NC    64         // num_colors
#define BN_EPS 1e-5

// R4 lesson: VGPR=16 -> 1 load in flight -> 960 GB/s. This round: 2 px/thread
// (float2, 512B/wave-load), 1024 blocks (4/CU, 16 waves/CU), explicit 8-deep
// load staging in the conv loop so ~8 wave-loads stay outstanding.

// ---------------------------------------------------------------------------
// k1: 1x1 conv (bias dropped — cancels under BN mean-subtraction), stash x
//     into the m-output region (channels 48..63), accumulate BN sum/sumsq.
// ---------------------------------------------------------------------------
__global__ __launch_bounds__(256, 4) void k_conv(const float* __restrict__ feat,
                                                 const float* __restrict__ wb,
                                                 double* __restrict__ gsum,
                                                 double* __restrict__ gsq,
                                                 float* __restrict__ xout)
{
    const int tid  = threadIdx.x;
    const int wave = tid >> 6, lane = tid & 63;
    const int b    = blockIdx.x >> 7;                  // 128 blocks per image
    const int p0   = ((blockIdx.x & 127) << 9) + (tid << 1); // 2 contiguous px
    const float* fb = feat + (ll)b * NCH * PPI + p0;

    float2 acc[NB];
#pragma unroll
    for (int o = 0; o < NB; ++o) acc[o] = make_float2(0.f, 0.f);

#pragma unroll 2
    for (int g = 0; g < 8; ++g) {                      // 8 channels per group
        float2 f[8];
#pragma unroll
        for (int i = 0; i < 8; ++i)
            f[i] = *reinterpret_cast<const float2*>(fb + (ll)(g * 8 + i) * PPI);
#pragma unroll
        for (int i = 0; i < 8; ++i) {
            const int c = g * 8 + i;
#pragma unroll
            for (int o = 0; o < NB; ++o) {
                float wv = wb[o * NCH + c];            // wave-uniform -> s_load
                acc[o].x = fmaf(f[i].x, wv, acc[o].x);
                acc[o].y = fmaf(f[i].y, wv, acc[o].y);
            }
        }
    }

    // stash x in m[b][48+o][p] (k2 consumes then overwrites)
#pragma unroll
    for (int o = 0; o < NB; ++o)
        *reinterpret_cast<float2*>(xout + ((ll)(b * NC + 48 + o)) * PPI + p0) = acc[o];

    // BN stats: wave shuffle-reduce, then block LDS reduce, then global atomic
    __shared__ float red_s[4][NB], red_q[4][NB];
#pragma unroll
    for (int o = 0; o < NB; ++o) {
        float s = acc[o].x + acc[o].y;
        float q = fmaf(acc[o].x, acc[o].x, acc[o].y * acc[o].y);
#pragma unroll
        for (int off = 32; off > 0; off >>= 1) {
            s += __shfl_down(s, off);
            q += __shfl_down(q, off);
        }
        if (lane == 0) { red_s[wave][o] = s; red_q[wave][o] = q; }
    }
    __syncthreads();
    if (tid < NB) {
        atomicAdd(&gsum[tid], (double)red_s[0][tid] + red_s[1][tid] + red_s[2][tid] + red_s[3][tid]);
        atomicAdd(&gsq[tid],  (double)red_q[0][tid] + red_q[1][tid] + red_q[2][tid] + red_q[3][tid]);
    }
}

// ---------------------------------------------------------------------------
// k2: BN+ReLU on x (read from m region), logits, top-4, softmax, dense m,
//     per-pixel records, palette num/den accumulation.
//     NOTE: m_out deliberately NOT __restrict__ — x lives inside it.
// ---------------------------------------------------------------------------
__global__ __launch_bounds__(256, 4) void k_mask(const float* __restrict__ img,
                                                 const float* __restrict__ gamma,
                                                 const float* __restrict__ beta,
                                                 const float* __restrict__ wm,
                                                 const double* __restrict__ gsum,
                                                 const double* __restrict__ gsq,
                                                 float* __restrict__ den_g,
                                                 float* __restrict__ num_g,
                                                 float* m_out,
                                                 unsigned* __restrict__ idx_out,
                                                 float* __restrict__ sm_out)
{
    __shared__ float weff_l[NC][NB];
    __shared__ float den_loc[4][NC];
    __shared__ float num_loc[4][3 * NC];
    __shared__ float scl_l[NB], shf_l[NB];

    const int tid  = threadIdx.x;
    const int wave = tid >> 6;
    const int b    = blockIdx.x >> 7;
    const int p0   = ((blockIdx.x & 127) << 9) + (tid << 1);

    for (int i = tid; i < NC * NB; i += 256) {
        int n = i >> 4, o = i & 15;
        weff_l[n][o] = 0.25f * (wm[n * NB + o] + wm[(64 + n) * NB + o] +
                                wm[(128 + n) * NB + o] + wm[(192 + n) * NB + o]);
    }
    for (int i = tid; i < 4 * NC; i += 256) den_loc[i >> 6][i & 63] = 0.f;
    for (int i = tid; i < 4 * 3 * NC; i += 256) num_loc[i / (3 * NC)][i % (3 * NC)] = 0.f;
    if (tid < NB) {
        double mu  = gsum[tid] * (1.0 / NPIX);
        double var = gsq[tid] * (1.0 / NPIX) - mu * mu;
        double sc  = (double)gamma[tid] / sqrt(var + BN_EPS);
        scl_l[tid] = (float)sc;
        shf_l[tid] = (float)((double)beta[tid] - mu * sc);
    }
    __syncthreads();

    // load x (16 float2 loads issued up front -> deep MLP), BN + ReLU
    float2 xx[NB];
#pragma unroll
    for (int o = 0; o < NB; ++o)
        xx[o] = *reinterpret_cast<const float2*>(m_out + ((ll)(b * NC + 48 + o)) * PPI + p0);
#pragma unroll
    for (int o = 0; o < NB; ++o) {
        float sc = scl_l[o], sh = shf_l[o];
        xx[o].x = fmaxf(0.f, fmaf(xx[o].x, sc, sh));
        xx[o].y = fmaxf(0.f, fmaf(xx[o].y, sc, sh));
    }

    // streaming branchless top-4 (strict > keeps jax lowest-index tie-break)
    float tv[2][4];
    int   ti[2][4];
#pragma unroll
    for (int j = 0; j < 2; ++j)
#pragma unroll
        for (int k = 0; k < 4; ++k) { tv[j][k] = -3.4e38f; ti[j][k] = 0; }

#pragma unroll 2
    for (int n = 0; n < NC; ++n) {
        const float* wr = weff_l[n];
        float2 v = make_float2(0.f, 0.f);
#pragma unroll
        for (int o = 0; o < NB; ++o) {
            float w = wr[o];
            v.x = fmaf(xx[o].x, w, v.x);
            v.y = fmaf(xx[o].y, w, v.y);
        }
        float vv[2] = {v.x, v.y};
#pragma unroll
        for (int j = 0; j < 2; ++j) {
            float x = vv[j];
            bool c0 = x > tv[j][0];
            bool c1 = x > tv[j][1];
            bool c2 = x > tv[j][2];
            bool c3 = x > tv[j][3];
            tv[j][3] = c2 ? tv[j][2] : fmaxf(x, tv[j][3]);
            ti[j][3] = c2 ? ti[j][2] : (c3 ? n : ti[j][3]);
            tv[j][2] = c1 ? tv[j][1] : fmaxf(x, tv[j][2]);
            ti[j][2] = c1 ? ti[j][1] : (c2 ? n : ti[j][2]);
            tv[j][1] = c0 ? tv[j][0] : fmaxf(x, tv[j][1]);
            ti[j][1] = c0 ? ti[j][0] : (c1 ? n : ti[j][1]);
            tv[j][0] = fmaxf(x, tv[j][0]);
            ti[j][0] = c0 ? n : ti[j][0];
        }
    }

    // softmax over kept 4 (tv sorted desc)
    float smx[2][4];
#pragma unroll
    for (int j = 0; j < 2; ++j) {
        float e1 = expf(tv[j][1] - tv[j][0]);
        float e2 = expf(tv[j][2] - tv[j][0]);
        float e3 = expf(tv[j][3] - tv[j][0]);
        float rz = 1.f / (1.f + e1 + e2 + e3);
        smx[j][0] = rz; smx[j][1] = e1 * rz; smx[j][2] = e2 * rz; smx[j][3] = e3 * rz;
    }

    // dense m write (overwrites the x stash at n=48..63 for this thread's pixels)
#define SEL(j, n) (((ti[j][0] == (n)) ? smx[j][0] : 0.f) + \
                   ((ti[j][1] == (n)) ? smx[j][1] : 0.f) + \
                   ((ti[j][2] == (n)) ? smx[j][2] : 0.f) + \
                   ((ti[j][3] == (n)) ? smx[j][3] : 0.f))
#pragma unroll 1
    for (int n = 0; n < NC; ++n) {
        float2 mv;
        mv.x = SEL(0, n); mv.y = SEL(1, n);
        *reinterpret_cast<float2*>(m_out + ((ll)(b * NC + n)) * PPI + p0) = mv;
    }
#undef SEL

    // per-pixel records (consumed by k3)
    ll gp = (ll)b * PPI + p0;
    uint2 pk;
    pk.x = (unsigned)ti[0][0] | ((unsigned)ti[0][1] << 8) | ((unsigned)ti[0][2] << 16) | ((unsigned)ti[0][3] << 24);
    pk.y = (unsigned)ti[1][0] | ((unsigned)ti[1][1] << 8) | ((unsigned)ti[1][2] << 16) | ((unsigned)ti[1][3] << 24);
    *reinterpret_cast<uint2*>(idx_out + gp) = pk;
#pragma unroll
    for (int k = 0; k < 4; ++k) {
        float2 sv = make_float2(smx[0][k], smx[1][k]);
        *reinterpret_cast<float2*>(sm_out + (ll)k * NPIX + gp) = sv;
    }

    // palette accumulation (per-wave LDS copies to cut contention)
    float2 i0 = *reinterpret_cast<const float2*>(img + ((ll)b * 3 + 0) * PPI + p0);
    float2 i1 = *reinterpret_cast<const float2*>(img + ((ll)b * 3 + 1) * PPI + p0);
    float2 i2 = *reinterpret_cast<const float2*>(img + ((ll)b * 3 + 2) * PPI + p0);
    float ir0[2] = {i0.x, i0.y};
    float ir1[2] = {i1.x, i1.y};
    float ir2[2] = {i2.x, i2.y};
#pragma unroll
    for (int j = 0; j < 2; ++j) {
#pragma unroll
        for (int k = 0; k < 4; ++k) {
            float s = smx[j][k];
            int   n = ti[j][k];
            atomicAdd(&den_loc[wave][n], s);
            atomicAdd(&num_loc[wave][0 * NC + n], s * ir0[j]);
            atomicAdd(&num_loc[wave][1 * NC + n], s * ir1[j]);
            atomicAdd(&num_loc[wave][2 * NC + n], s * ir2[j]);
        }
    }
    __syncthreads();
    if (tid < NC)
        atomicAdd(&den_g[b * NC + tid],
                  den_loc[0][tid] + den_loc[1][tid] + den_loc[2][tid] + den_loc[3][tid]);
    if (tid < 3 * NC)
        atomicAdd(&num_g[(ll)b * 3 * NC + tid],
                  num_loc[0][tid] + num_loc[1][tid] + num_loc[2][tid] + num_loc[3][tid]);
}

// ---------------------------------------------------------------------------
// k3: palette finalize (per-block in LDS) + write palette + reconstruction
// ---------------------------------------------------------------------------
__global__ __launch_bounds__(256, 4) void k_recon(const unsigned* __restrict__ idx_in,
                                                  const float* __restrict__ sm_in,
                                                  const float* __restrict__ den_g,
                                                  const float* __restrict__ num_g,
                                                  float* __restrict__ pal_out,
                                                  float* __restrict__ t_out)
{
    __shared__ float pal_l[3][NC];
    __shared__ float rden[NC];
    const int tid = threadIdx.x;
    const int b   = blockIdx.x >> 7;
    const int p0  = ((blockIdx.x & 127) << 9) + (tid << 1);

    if (tid < NC) rden[tid] = 1.f / (den_g[b * NC + tid] + 1e-8f);
    __syncthreads();
    if (tid < 3 * NC) {
        int c = tid >> 6, n = tid & 63;
        pal_l[c][n] = num_g[(ll)b * 3 * NC + tid] * rden[n];
    }
    __syncthreads();
    if ((blockIdx.x & 127) == 0 && tid < 3 * NC)
        pal_out[b * 3 * NC + tid] = pal_l[tid >> 6][tid & 63];

    ll gp = (ll)b * PPI + p0;
    uint2  pk = *reinterpret_cast<const uint2*>(idx_in + gp);
    float2 s0 = *reinterpret_cast<const float2*>(sm_in + gp);
    float2 s1 = *reinterpret_cast<const float2*>(sm_in + (ll)NPIX + gp);
    float2 s2 = *reinterpret_cast<const float2*>(sm_in + 2ll * NPIX + gp);
    float2 s3 = *reinterpret_cast<const float2*>(sm_in + 3ll * NPIX + gp);
    unsigned pkv[2] = {pk.x, pk.y};
    float sA[2][4] = {{s0.x, s1.x, s2.x, s3.x}, {s0.y, s1.y, s2.y, s3.y}};

#pragma unroll
    for (int c = 0; c < 3; ++c) {
        float2 t;
#pragma unroll
        for (int j = 0; j < 2; ++j) {
            unsigned pv = pkv[j];
            float v = sA[j][0] * pal_l[c][pv & 255] + sA[j][1] * pal_l[c][(pv >> 8) & 255] +
                      sA[j][2] * pal_l[c][(pv >> 16) & 255] + sA[j][3] * pal_l[c][pv >> 24];
            (j == 0 ? t.x : t.y) = v;
        }
        *reinterpret_cast<float2*>(t_out + ((ll)b * 3 + c) * PPI + p0) = t;
    }
}

// ---------------------------------------------------------------------------
extern "C" void kernel_launch(void* const* d_in, const int* in_sizes, int n_in,
                              void* d_out, int out_size, void* d_ws, size_t ws_size,
                              hipStream_t stream)
{
    const float* img   = (const float*)d_in[0];
    const float* feat  = (const float*)d_in[1];
    const float* wb    = (const float*)d_in[2];
    // d_in[3] = b_bneck: unused — bias cancels under BatchNorm mean-subtraction
    const float* gamma = (const float*)d_in[4];
    const float* beta  = (const float*)d_in[5];
    const float* wm    = (const float*)d_in[6];

    char* ws = (char*)d_ws;
    double*   gsum  = (double*)(ws + 0);      // 16 doubles
    double*   gsq   = (double*)(ws + 128);    // 16 doubles
    float*    den_g = (float*)(ws + 256);     // 8*64 floats
    float*    num_g = (float*)(ws + 2304);    // 8*3*64 floats  (end: 8448)
    unsigned* idx4  = (unsigned*)(ws + 8448);             // NPIX u32
    float*    smarr = (float*)(ws + 8448 + 4ll * NPIX);   // 4*NPIX f32

    float* t_out   = (float*)d_out;               // [8,3,256,256]
    float* m_out   = t_out + 3ll * NPIX;          // [8,64,256,256]
    float* pal_out = m_out + 64ll * NPIX;         // [8,3,64,1,1]

    hipMemsetAsync(ws, 0, 8448, stream);          // zero atomic accumulators

    k_conv <<<NPIX / 512, 256, 0, stream>>>(feat, wb, gsum, gsq, m_out);
    k_mask <<<NPIX / 512, 256, 0, stream>>>(img, gamma, beta, wm, gsum, gsq,
                                            den_g, num_g, m_out, idx4, smarr);
    k_recon<<<NPIX / 512, 256, 0, stream>>>(idx4, smarr, den_g, num_g, pal_out, t_out);
}